// Round 6
// baseline (1300.629 us; speedup 1.0000x reference)
//
#include <hip/hip_runtime.h>

#define NN 100000
#define NE 1600000
#define NBK 782  // ceil(NN/128) 128-node buckets

typedef __bf16 bf16x2 __attribute__((ext_vector_type(2)));
typedef __bf16 bf16x4 __attribute__((ext_vector_type(4)));
typedef __bf16 bf16x8 __attribute__((ext_vector_type(8)));
typedef float f32x4 __attribute__((ext_vector_type(4)));

constexpr int SCAN_BLOCKS = (NN + 255) / 256;  // 391

// ---------------- bucketed CSR build ----------------
// Replaces the old k_count/k_fill: old k_fill scattered 4B writes across 6.4 MB
// -> 16x write amplification (107 MB HBM writes, ~125 us). Bucketing confines
// scattered writes to L2-resident regions (~1x amplification).

__global__ __launch_bounds__(256) void k_bcount(const int* __restrict__ dst, int* __restrict__ bcount) {
  int e = blockIdx.x * 256 + threadIdx.x;
  if (e < NE) atomicAdd(&bcount[dst[e] >> 7], 1);
}

__global__ __launch_bounds__(1024) void k_bscan(const int* __restrict__ bcount, int* __restrict__ bptr,
                                                int* __restrict__ bcursor) {
  __shared__ int s[1024];
  int tid = threadIdx.x;
  int v = (tid < NBK) ? bcount[tid] : 0;
  s[tid] = v;
  __syncthreads();
  for (int off = 1; off < 1024; off <<= 1) {
    int t = (tid >= off) ? s[tid - off] : 0;
    __syncthreads();
    s[tid] += t;
    __syncthreads();
  }
  if (tid < NBK) {
    bptr[tid + 1] = s[tid];
    bcursor[tid] = s[tid] - v;  // exclusive
  }
  if (tid == 0) bptr[0] = 0;
}

__global__ __launch_bounds__(256) void k_bscatter(const int* __restrict__ src, const int* __restrict__ dst,
                                                  int* __restrict__ bcursor, int2* __restrict__ bucketed) {
  int e = blockIdx.x * 256 + threadIdx.x;
  if (e < NE) {
    int d = dst[e];
    int pos = atomicAdd(&bcursor[d >> 7], 1);
    bucketed[pos] = make_int2(src[e], d);
  }
}

// one block per bucket: LDS histogram -> per-node degree + dis (no global atomics)
__global__ __launch_bounds__(256) void k_deg(const int2* __restrict__ bucketed, const int* __restrict__ bptr,
                                             int* __restrict__ counts, float* __restrict__ dis) {
  __shared__ int deg[128];
  int b = blockIdx.x, tid = threadIdx.x;
  int nb0 = b << 7;
  if (tid < 128) deg[tid] = 0;
  __syncthreads();
  int beg = bptr[b], end = bptr[b + 1];
  for (int e = beg + tid; e < end; e += 256) atomicAdd(&deg[bucketed[e].y & 127], 1);
  __syncthreads();
  if (tid < 128 && nb0 + tid < NN) {
    int dg = deg[tid];
    counts[nb0 + tid] = dg;
    dis[nb0 + tid] = rsqrtf((float)(dg + 1));  // +1 self-loop
  }
}

// one block per bucket: LDS cursors from row_ptr; csr region (~8 KB) is L2-resident
__global__ __launch_bounds__(256) void k_csrfill(const int2* __restrict__ bucketed, const int* __restrict__ bptr,
                                                 const int* __restrict__ row_ptr, int* __restrict__ csr_src) {
  __shared__ int cur[128];
  int b = blockIdx.x, tid = threadIdx.x;
  int nb0 = b << 7;
  if (tid < 128 && nb0 + tid < NN) cur[tid] = row_ptr[nb0 + tid];
  __syncthreads();
  int beg = bptr[b], end = bptr[b + 1];
  for (int e = beg + tid; e < end; e += 256) {
    int2 ed = bucketed[e];
    int pos = atomicAdd(&cur[ed.y & 127], 1);
    csr_src[pos] = ed.x;
  }
}

// ---------------- node-level scan (counts -> row_ptr) ----------------

__global__ __launch_bounds__(256) void k_scan_block(const int* __restrict__ counts, int* __restrict__ row_ptr,
                                                    int* __restrict__ bsums) {
  __shared__ int s[256];
  int tid = threadIdx.x;
  int i = blockIdx.x * 256 + tid;
  int v = (i < NN) ? counts[i] : 0;
  s[tid] = v;
  __syncthreads();
  for (int off = 1; off < 256; off <<= 1) {
    int t = (tid >= off) ? s[tid - off] : 0;
    __syncthreads();
    s[tid] += t;
    __syncthreads();
  }
  if (i < NN) row_ptr[i + 1] = s[tid];
  if (tid == 255) bsums[blockIdx.x] = s[255];
}

__global__ __launch_bounds__(512) void k_scan_bsums(int* __restrict__ bsums) {
  __shared__ int s[512];
  int tid = threadIdx.x;
  int v = (tid < SCAN_BLOCKS) ? bsums[tid] : 0;
  s[tid] = v;
  __syncthreads();
  for (int off = 1; off < 512; off <<= 1) {
    int t = (tid >= off) ? s[tid - off] : 0;
    __syncthreads();
    s[tid] += t;
    __syncthreads();
  }
  bsums[tid] = s[tid];
}

__global__ __launch_bounds__(256) void k_scan_add(int* __restrict__ row_ptr, const int* __restrict__ bsums) {
  int i = blockIdx.x * 256 + threadIdx.x;
  if (i < NN && blockIdx.x > 0) row_ptr[i + 1] += bsums[blockIdx.x - 1];
  if (i == 0) row_ptr[0] = 0;
}

// ---------------- bf16 MFMA GEMM: tmp[m,n] = dis[m] * (xform(A[m,:]) @ W)[n] ----------------
// MODE 0: A fp32 [*,128], no transform (layer 1: A = x).
// MODE 2: A bf16 [*,128] (agg from previous layer, lives in d_out); xform = relu(a + bias[k]).
// W fp32 [128,BN] row-major, bias fp32. tmp out bf16 [*,BN], scaled by dis[row].

template <int BN, int MODE>
__global__ __launch_bounds__(256) void k_gemm(const void* __restrict__ Av, const float* __restrict__ W,
                                              const float* __restrict__ bias, const float* __restrict__ dis,
                                              __bf16* __restrict__ out) {
  constexpr int LDK = 72;  // 64 + 8 pad: row stride 144 B -> bank rotation; 2-way conflict = free
  constexpr int NSH = (BN == 128) ? 7 : 6;
  constexpr int NT = BN / 32;  // 16-wide n-tiles per wave (wave tile = 64 x BN/2)
  __shared__ __bf16 lA[128 * LDK];
  __shared__ __bf16 lB[BN * LDK];

  const int tid = threadIdx.x;
  const int rowBase = blockIdx.x * 128;
  const int lane = tid & 63;
  const int wid = tid >> 6;
  const int wm = (wid & 1) * 64;
  const int wn = (wid >> 1) * (BN / 2);
  const int lm = lane & 15;
  const int kg = lane >> 4;

  f32x4 acc[4][NT] = {};

  for (int kb = 0; kb < 128; kb += 64) {
    if constexpr (MODE == 0) {
      const float* A = (const float*)Av;
      for (int i = tid; i < 128 * 16; i += 256) {
        int r = i >> 4;
        int c4 = (i & 15) * 4;
        int gr = rowBase + r;
        float4 v = make_float4(0.f, 0.f, 0.f, 0.f);
        if (gr < NN) v = *(const float4*)(A + (size_t)gr * 128 + kb + c4);
        bf16x4 bv = {(__bf16)v.x, (__bf16)v.y, (__bf16)v.z, (__bf16)v.w};
        *(bf16x4*)&lA[r * LDK + c4] = bv;
      }
    } else {
      const __bf16* A = (const __bf16*)Av;
      for (int i = tid; i < 128 * 8; i += 256) {
        int r = i >> 3;
        int c8 = (i & 7) * 8;
        int gr = rowBase + r;
        int gk = kb + c8;
        bf16x8 v = {};
        if (gr < NN) v = *(const bf16x8*)(A + (size_t)gr * 128 + gk);
        bf16x8 o;
#pragma unroll
        for (int j = 0; j < 8; ++j) o[j] = (__bf16)fmaxf((float)v[j] + bias[gk + j], 0.f);
        *(bf16x8*)&lA[r * LDK + c8] = o;
      }
    }
    // stage W tile transposed: lB[n][k] = W[kb+k][n]  (coalesced over n)
    for (int i = tid; i < 64 * BN; i += 256) {
      int n = i & (BN - 1);
      int k = i >> NSH;
      lB[n * LDK + k] = (__bf16)W[(size_t)(kb + k) * BN + n];
    }
    __syncthreads();
#pragma unroll
    for (int kk = 0; kk < 64; kk += 32) {
      bf16x8 af[4], bfr[NT];
#pragma unroll
      for (int tm = 0; tm < 4; ++tm)
        af[tm] = *(const bf16x8*)&lA[(wm + tm * 16 + lm) * LDK + kk + kg * 8];
#pragma unroll
      for (int tn = 0; tn < NT; ++tn)
        bfr[tn] = *(const bf16x8*)&lB[(wn + tn * 16 + lm) * LDK + kk + kg * 8];
#pragma unroll
      for (int tm = 0; tm < 4; ++tm)
#pragma unroll
        for (int tn = 0; tn < NT; ++tn)
          acc[tm][tn] = __builtin_amdgcn_mfma_f32_16x16x32_bf16(af[tm], bfr[tn], acc[tm][tn], 0, 0, 0);
    }
    __syncthreads();
  }

  // epilogue: C/D layout col=lane&15, row=(lane>>4)*4+reg; scale by dis[row], store bf16
#pragma unroll
  for (int tm = 0; tm < 4; ++tm) {
    int r0 = rowBase + wm + tm * 16 + kg * 4;
#pragma unroll
    for (int tn = 0; tn < NT; ++tn) {
      int c0 = wn + tn * 16 + lm;
#pragma unroll
      for (int r = 0; r < 4; ++r) {
        int gr = r0 + r;
        if (gr < NN) out[(size_t)gr * BN + c0] = (__bf16)(acc[tm][tn][r] * dis[gr]);
      }
    }
  }
}

// ---------------- pull aggregation: agg[n] = dis[n] * (sum_{s in in(n)} tmp[s] + tmp[n]) ----------------
// tmp rows already carry dis[src]. One wave per node; 64-edge batches broadcast via shfl.
// F=128: accumulate fp32, write bf16 (agg lives in d_out). F=64: write fp32 (final agg in d_out).

template <int F>
__global__ __launch_bounds__(256) void k_agg(const __bf16* __restrict__ tmp, const int* __restrict__ row_ptr,
                                             const int* __restrict__ csr_src, const float* __restrict__ dis,
                                             void* __restrict__ aggv) {
  int wid = (blockIdx.x * 256 + threadIdx.x) >> 6;
  int lane = threadIdx.x & 63;
  if (wid >= NN) return;
  int beg = row_ptr[wid];
  int end = row_ptr[wid + 1];
  if constexpr (F == 128) {
    bf16x2 sv = *(const bf16x2*)&tmp[(size_t)wid * 128 + lane * 2];
    float ax = (float)sv[0], ay = (float)sv[1];
    for (int base = beg; base < end; base += 64) {
      int cnt = min(64, end - base);
      int sidx = (base + lane < end) ? csr_src[base + lane] : 0;
      for (int j = 0; j < cnt; ++j) {
        int s = __shfl(sidx, j);
        bf16x2 v = *(const bf16x2*)&tmp[(size_t)s * 128 + lane * 2];
        ax += (float)v[0];
        ay += (float)v[1];
      }
    }
    float d = dis[wid];
    bf16x2 o = {(__bf16)(ax * d), (__bf16)(ay * d)};
    *(bf16x2*)((__bf16*)aggv + (size_t)wid * 128 + lane * 2) = o;
  } else {
    float a = (float)tmp[(size_t)wid * 64 + lane];
    for (int base = beg; base < end; base += 64) {
      int cnt = min(64, end - base);
      int sidx = (base + lane < end) ? csr_src[base + lane] : 0;
      for (int j = 0; j < cnt; ++j) {
        int s = __shfl(sidx, j);
        a += (float)tmp[(size_t)s * 64 + lane];
      }
    }
    ((float*)aggv)[(size_t)wid * 64 + lane] = a * dis[wid];
  }
}

// ---------------- final (in-place on d_out): relu(agg + b2) -> log_softmax, fp32 ----------------

__global__ __launch_bounds__(256) void k_final(float* __restrict__ buf, const float* __restrict__ b2) {
  int wid = (blockIdx.x * 256 + threadIdx.x) >> 6;
  int lane = threadIdx.x & 63;
  if (wid >= NN) return;
  float v = fmaxf(buf[(size_t)wid * 64 + lane] + b2[lane], 0.f);
  float m = v;
#pragma unroll
  for (int off = 32; off > 0; off >>= 1) m = fmaxf(m, __shfl_xor(m, off));
  float e = expf(v - m);
  float ss = e;
#pragma unroll
  for (int off = 32; off > 0; off >>= 1) ss += __shfl_xor(ss, off);
  buf[(size_t)wid * 64 + lane] = (v - m) - logf(ss);
}

// ---------------- launch ----------------

extern "C" void kernel_launch(void* const* d_in, const int* in_sizes, int n_in,
                              void* d_out, int out_size, void* d_ws, size_t ws_size,
                              hipStream_t stream) {
  const float* x  = (const float*)d_in[0];
  const int*   ei = (const int*)d_in[1];
  const float* W0 = (const float*)d_in[2];
  const float* b0 = (const float*)d_in[3];
  const float* W1 = (const float*)d_in[4];
  const float* b1 = (const float*)d_in[5];
  const float* W2 = (const float*)d_in[6];
  const float* b2 = (const float*)d_in[7];
  const int* esrc = ei;        // edge_index[0]
  const int* edst = ei + NE;   // edge_index[1]

  // Workspace (~33.6 MB). bucketed edge array (12.8 MB) aliases tmp (dead until first GEMM).
  char* p = (char*)d_ws;
  auto alloc = [&](size_t bytes) {
    char* q = p;
    p += (bytes + 255) & ~(size_t)255;
    return q;
  };
  int*    counts  = (int*)alloc((size_t)NN * 4);            // 0.4 MB
  float*  dis     = (float*)alloc((size_t)NN * 4);          // 0.4 MB
  int*    row_ptr = (int*)alloc((size_t)(NN + 1) * 4);      // 0.4 MB
  int*    bsums   = (int*)alloc(512 * 4);
  int*    bcount  = (int*)alloc(NBK * 4);
  int*    bptr    = (int*)alloc((NBK + 1) * 4);
  int*    bcursor = (int*)alloc(NBK * 4);
  int*    csr_src = (int*)alloc((size_t)NE * 4);            // 6.4 MB
  __bf16* tmp     = (__bf16*)alloc((size_t)NN * 128 * 2);   // 25.6 MB
  int2*   bucketed = (int2*)tmp;                            // 12.8 MB alias
  // agg lives in d_out (100000*64*4 B): layers 1-2 bf16 [NN,128], layer 3 fp32 [NN,64].

  hipMemsetAsync(bcount, 0, NBK * 4, stream);

  int eblocks = (NE + 255) / 256;
  k_bcount<<<eblocks, 256, 0, stream>>>(edst, bcount);
  k_bscan<<<1, 1024, 0, stream>>>(bcount, bptr, bcursor);
  k_bscatter<<<eblocks, 256, 0, stream>>>(esrc, edst, bcursor, bucketed);
  k_deg<<<NBK, 256, 0, stream>>>(bucketed, bptr, counts, dis);
  k_scan_block<<<SCAN_BLOCKS, 256, 0, stream>>>(counts, row_ptr, bsums);
  k_scan_bsums<<<1, 512, 0, stream>>>(bsums);
  k_scan_add<<<SCAN_BLOCKS, 256, 0, stream>>>(row_ptr, bsums);
  k_csrfill<<<NBK, 256, 0, stream>>>(bucketed, bptr, row_ptr, csr_src);

  int gblocks = (NN + 127) / 128;
  int ablocks = (NN * 64 + 255) / 256;

  k_gemm<128, 0><<<gblocks, 256, 0, stream>>>(x, W0, nullptr, dis, tmp);
  k_agg<128><<<ablocks, 256, 0, stream>>>(tmp, row_ptr, csr_src, dis, d_out);  // agg1 bf16 in d_out

  k_gemm<128, 2><<<gblocks, 256, 0, stream>>>(d_out, W1, b0, dis, tmp);
  k_agg<128><<<ablocks, 256, 0, stream>>>(tmp, row_ptr, csr_src, dis, d_out);  // agg2 bf16 in d_out

  k_gemm<64, 2><<<gblocks, 256, 0, stream>>>(d_out, W2, b1, dis, tmp);
  k_agg<64><<<ablocks, 256, 0, stream>>>(tmp, row_ptr, csr_src, dis, d_out);   // agg3 fp32 in d_out

  k_final<<<ablocks, 256, 0, stream>>>((float*)d_out, b2);                     // in-place
}

// Round 7
// 580.818 us; speedup vs baseline: 2.2393x; 2.2393x over previous
//
#include <hip/hip_runtime.h>

#define NN 100000
#define NE 1600000
#define NBK 782   // ceil(NN/128) 128-node buckets
#define NBLK 256  // persistent blocks for counting sort
#define CHUNK ((NE + NBLK - 1) / NBLK)  // 6250 (exact: 256*6250 = 1.6M)

typedef __bf16 bf16x2 __attribute__((ext_vector_type(2)));
typedef __bf16 bf16x4 __attribute__((ext_vector_type(4)));
typedef __bf16 bf16x8 __attribute__((ext_vector_type(8)));
typedef float f32x4 __attribute__((ext_vector_type(4)));

constexpr int SCAN_BLOCKS = (NN + 255) / 256;  // 391

// ---------------- privatized counting sort by dst-bucket ----------------
// r6 lesson: 1.6M global atomics on 782 packed counters serialize (~33k/line
// * ~11ns = 360us). This build has ZERO contended global atomics: per-block
// LDS histograms + per-(bin,block) reserved ranges.

// k1: per-block LDS histogram of its edge chunk; contiguous row write.
__global__ __launch_bounds__(256) void k1_hist(const int* __restrict__ dst, int* __restrict__ bhist) {
  __shared__ int h[NBK];
  int tid = threadIdx.x, b = blockIdx.x;
  for (int i = tid; i < NBK; i += 256) h[i] = 0;
  __syncthreads();
  int base = b * CHUNK, end = min(base + CHUNK, NE);
  for (int e = base + tid; e < end; e += 256) atomicAdd(&h[dst[e] >> 7], 1);
  __syncthreads();
  for (int i = tid; i < NBK; i += 256) bhist[b * NBK + i] = h[i];  // [block][bin] contiguous
}

// kA: per-bin total over blocks (one block per bin, strided reads).
__global__ __launch_bounds__(256) void kA_btot(const int* __restrict__ bhist, int* __restrict__ btot) {
  __shared__ int s[256];
  int bin = blockIdx.x, tid = threadIdx.x;
  s[tid] = bhist[tid * NBK + bin];  // NBLK == 256 == blockDim
  __syncthreads();
  for (int off = 128; off > 0; off >>= 1) {
    if (tid < off) s[tid] += s[tid + off];
    __syncthreads();
  }
  if (tid == 0) btot[bin] = s[0];
}

// kB: prefix scan over 782 bin totals -> bptr.
__global__ __launch_bounds__(1024) void kB_bscan(const int* __restrict__ btot, int* __restrict__ bptr) {
  __shared__ int s[1024];
  int tid = threadIdx.x;
  int v = (tid < NBK) ? btot[tid] : 0;
  s[tid] = v;
  __syncthreads();
  for (int off = 1; off < 1024; off <<= 1) {
    int t = (tid >= off) ? s[tid - off] : 0;
    __syncthreads();
    s[tid] += t;
    __syncthreads();
  }
  if (tid < NBK) bptr[tid + 1] = s[tid];
  if (tid == 0) bptr[0] = 0;
}

// kC: per-bin exclusive prefix over blocks + bptr[bin] -> blockbase[bin][block] (contiguous write).
__global__ __launch_bounds__(256) void kC_bbase(const int* __restrict__ bhist, const int* __restrict__ bptr,
                                                int* __restrict__ blockbase) {
  __shared__ int s[256];
  int bin = blockIdx.x, tid = threadIdx.x;
  int v = bhist[tid * NBK + bin];
  s[tid] = v;
  __syncthreads();
  for (int off = 1; off < 256; off <<= 1) {
    int t = (tid >= off) ? s[tid - off] : 0;
    __syncthreads();
    s[tid] += t;
    __syncthreads();
  }
  blockbase[bin * NBLK + tid] = bptr[bin] + s[tid] - v;  // exclusive
}

// k3: scatter edges into bucket-contiguous segments via LDS cursors (no global atomics).
__global__ __launch_bounds__(256) void k3_scatter(const int* __restrict__ src, const int* __restrict__ dst,
                                                  const int* __restrict__ blockbase, int2* __restrict__ bucketed) {
  __shared__ int cur[NBK];
  int tid = threadIdx.x, b = blockIdx.x;
  for (int i = tid; i < NBK; i += 256) cur[i] = blockbase[i * NBLK + b];
  __syncthreads();
  int base = b * CHUNK, end = min(base + CHUNK, NE);
  for (int e = base + tid; e < end; e += 256) {
    int d = dst[e];
    int pos = atomicAdd(&cur[d >> 7], 1);
    bucketed[pos] = make_int2(src[e], d);
  }
}

// one block per bucket: LDS histogram -> per-node degree + dis (no global atomics)
__global__ __launch_bounds__(256) void k_deg(const int2* __restrict__ bucketed, const int* __restrict__ bptr,
                                             int* __restrict__ counts, float* __restrict__ dis) {
  __shared__ int deg[128];
  int b = blockIdx.x, tid = threadIdx.x;
  int nb0 = b << 7;
  if (tid < 128) deg[tid] = 0;
  __syncthreads();
  int beg = bptr[b], end = bptr[b + 1];
  for (int e = beg + tid; e < end; e += 256) atomicAdd(&deg[bucketed[e].y & 127], 1);
  __syncthreads();
  if (tid < 128 && nb0 + tid < NN) {
    int dg = deg[tid];
    counts[nb0 + tid] = dg;
    dis[nb0 + tid] = rsqrtf((float)(dg + 1));  // +1 self-loop
  }
}

// one block per bucket: LDS cursors from row_ptr; csr region (~8 KB) is L2-resident
__global__ __launch_bounds__(256) void k_csrfill(const int2* __restrict__ bucketed, const int* __restrict__ bptr,
                                                 const int* __restrict__ row_ptr, int* __restrict__ csr_src) {
  __shared__ int cur[128];
  int b = blockIdx.x, tid = threadIdx.x;
  int nb0 = b << 7;
  if (tid < 128 && nb0 + tid < NN) cur[tid] = row_ptr[nb0 + tid];
  __syncthreads();
  int beg = bptr[b], end = bptr[b + 1];
  for (int e = beg + tid; e < end; e += 256) {
    int2 ed = bucketed[e];
    int pos = atomicAdd(&cur[ed.y & 127], 1);
    csr_src[pos] = ed.x;
  }
}

// ---------------- node-level scan (counts -> row_ptr) ----------------

__global__ __launch_bounds__(256) void k_scan_block(const int* __restrict__ counts, int* __restrict__ row_ptr,
                                                    int* __restrict__ bsums) {
  __shared__ int s[256];
  int tid = threadIdx.x;
  int i = blockIdx.x * 256 + tid;
  int v = (i < NN) ? counts[i] : 0;
  s[tid] = v;
  __syncthreads();
  for (int off = 1; off < 256; off <<= 1) {
    int t = (tid >= off) ? s[tid - off] : 0;
    __syncthreads();
    s[tid] += t;
    __syncthreads();
  }
  if (i < NN) row_ptr[i + 1] = s[tid];
  if (tid == 255) bsums[blockIdx.x] = s[255];
}

__global__ __launch_bounds__(512) void k_scan_bsums(int* __restrict__ bsums) {
  __shared__ int s[512];
  int tid = threadIdx.x;
  int v = (tid < SCAN_BLOCKS) ? bsums[tid] : 0;
  s[tid] = v;
  __syncthreads();
  for (int off = 1; off < 512; off <<= 1) {
    int t = (tid >= off) ? s[tid - off] : 0;
    __syncthreads();
    s[tid] += t;
    __syncthreads();
  }
  bsums[tid] = s[tid];
}

__global__ __launch_bounds__(256) void k_scan_add(int* __restrict__ row_ptr, const int* __restrict__ bsums) {
  int i = blockIdx.x * 256 + threadIdx.x;
  if (i < NN && blockIdx.x > 0) row_ptr[i + 1] += bsums[blockIdx.x - 1];
  if (i == 0) row_ptr[0] = 0;
}

// ---------------- bf16 MFMA GEMM: tmp[m,n] = dis[m] * (xform(A[m,:]) @ W)[n] ----------------
// MODE 0: A fp32 [*,128], no transform (layer 1: A = x).
// MODE 2: A bf16 [*,128] (agg from previous layer, lives in d_out); xform = relu(a + bias[k]).
// W fp32 [128,BN] row-major, bias fp32. tmp out bf16 [*,BN], scaled by dis[row].

template <int BN, int MODE>
__global__ __launch_bounds__(256) void k_gemm(const void* __restrict__ Av, const float* __restrict__ W,
                                              const float* __restrict__ bias, const float* __restrict__ dis,
                                              __bf16* __restrict__ out) {
  constexpr int LDK = 72;  // 64 + 8 pad: row stride 144 B -> bank rotation; 2-way conflict = free
  constexpr int NSH = (BN == 128) ? 7 : 6;
  constexpr int NT = BN / 32;  // 16-wide n-tiles per wave (wave tile = 64 x BN/2)
  __shared__ __bf16 lA[128 * LDK];
  __shared__ __bf16 lB[BN * LDK];

  const int tid = threadIdx.x;
  const int rowBase = blockIdx.x * 128;
  const int lane = tid & 63;
  const int wid = tid >> 6;
  const int wm = (wid & 1) * 64;
  const int wn = (wid >> 1) * (BN / 2);
  const int lm = lane & 15;
  const int kg = lane >> 4;

  f32x4 acc[4][NT] = {};

  for (int kb = 0; kb < 128; kb += 64) {
    if constexpr (MODE == 0) {
      const float* A = (const float*)Av;
      for (int i = tid; i < 128 * 16; i += 256) {
        int r = i >> 4;
        int c4 = (i & 15) * 4;
        int gr = rowBase + r;
        float4 v = make_float4(0.f, 0.f, 0.f, 0.f);
        if (gr < NN) v = *(const float4*)(A + (size_t)gr * 128 + kb + c4);
        bf16x4 bv = {(__bf16)v.x, (__bf16)v.y, (__bf16)v.z, (__bf16)v.w};
        *(bf16x4*)&lA[r * LDK + c4] = bv;
      }
    } else {
      const __bf16* A = (const __bf16*)Av;
      for (int i = tid; i < 128 * 8; i += 256) {
        int r = i >> 3;
        int c8 = (i & 7) * 8;
        int gr = rowBase + r;
        int gk = kb + c8;
        bf16x8 v = {};
        if (gr < NN) v = *(const bf16x8*)(A + (size_t)gr * 128 + gk);
        bf16x8 o;
#pragma unroll
        for (int j = 0; j < 8; ++j) o[j] = (__bf16)fmaxf((float)v[j] + bias[gk + j], 0.f);
        *(bf16x8*)&lA[r * LDK + c8] = o;
      }
    }
    // stage W tile transposed: lB[n][k] = W[kb+k][n]  (coalesced over n)
    for (int i = tid; i < 64 * BN; i += 256) {
      int n = i & (BN - 1);
      int k = i >> NSH;
      lB[n * LDK + k] = (__bf16)W[(size_t)(kb + k) * BN + n];
    }
    __syncthreads();
#pragma unroll
    for (int kk = 0; kk < 64; kk += 32) {
      bf16x8 af[4], bfr[NT];
#pragma unroll
      for (int tm = 0; tm < 4; ++tm)
        af[tm] = *(const bf16x8*)&lA[(wm + tm * 16 + lm) * LDK + kk + kg * 8];
#pragma unroll
      for (int tn = 0; tn < NT; ++tn)
        bfr[tn] = *(const bf16x8*)&lB[(wn + tn * 16 + lm) * LDK + kk + kg * 8];
#pragma unroll
      for (int tm = 0; tm < 4; ++tm)
#pragma unroll
        for (int tn = 0; tn < NT; ++tn)
          acc[tm][tn] = __builtin_amdgcn_mfma_f32_16x16x32_bf16(af[tm], bfr[tn], acc[tm][tn], 0, 0, 0);
    }
    __syncthreads();
  }

  // epilogue: C/D layout col=lane&15, row=(lane>>4)*4+reg; scale by dis[row], store bf16
#pragma unroll
  for (int tm = 0; tm < 4; ++tm) {
    int r0 = rowBase + wm + tm * 16 + kg * 4;
#pragma unroll
    for (int tn = 0; tn < NT; ++tn) {
      int c0 = wn + tn * 16 + lm;
#pragma unroll
      for (int r = 0; r < 4; ++r) {
        int gr = r0 + r;
        if (gr < NN) out[(size_t)gr * BN + c0] = (__bf16)(acc[tm][tn][r] * dis[gr]);
      }
    }
  }
}

// ---------------- pull aggregation: agg[n] = dis[n] * (sum_{s in in(n)} tmp[s] + tmp[n]) ----------------
// tmp rows already carry dis[src]. One wave per node; 64-edge batches broadcast via shfl.
// F=128: accumulate fp32, write bf16 (agg lives in d_out). F=64: write fp32 (final agg in d_out).

template <int F>
__global__ __launch_bounds__(256) void k_agg(const __bf16* __restrict__ tmp, const int* __restrict__ row_ptr,
                                             const int* __restrict__ csr_src, const float* __restrict__ dis,
                                             void* __restrict__ aggv) {
  int wid = (blockIdx.x * 256 + threadIdx.x) >> 6;
  int lane = threadIdx.x & 63;
  if (wid >= NN) return;
  int beg = row_ptr[wid];
  int end = row_ptr[wid + 1];
  if constexpr (F == 128) {
    bf16x2 sv = *(const bf16x2*)&tmp[(size_t)wid * 128 + lane * 2];
    float ax = (float)sv[0], ay = (float)sv[1];
    for (int base = beg; base < end; base += 64) {
      int cnt = min(64, end - base);
      int sidx = (base + lane < end) ? csr_src[base + lane] : 0;
      for (int j = 0; j < cnt; ++j) {
        int s = __shfl(sidx, j);
        bf16x2 v = *(const bf16x2*)&tmp[(size_t)s * 128 + lane * 2];
        ax += (float)v[0];
        ay += (float)v[1];
      }
    }
    float d = dis[wid];
    bf16x2 o = {(__bf16)(ax * d), (__bf16)(ay * d)};
    *(bf16x2*)((__bf16*)aggv + (size_t)wid * 128 + lane * 2) = o;
  } else {
    float a = (float)tmp[(size_t)wid * 64 + lane];
    for (int base = beg; base < end; base += 64) {
      int cnt = min(64, end - base);
      int sidx = (base + lane < end) ? csr_src[base + lane] : 0;
      for (int j = 0; j < cnt; ++j) {
        int s = __shfl(sidx, j);
        a += (float)tmp[(size_t)s * 64 + lane];
      }
    }
    ((float*)aggv)[(size_t)wid * 64 + lane] = a * dis[wid];
  }
}

// ---------------- final (in-place on d_out): relu(agg + b2) -> log_softmax, fp32 ----------------

__global__ __launch_bounds__(256) void k_final(float* __restrict__ buf, const float* __restrict__ b2) {
  int wid = (blockIdx.x * 256 + threadIdx.x) >> 6;
  int lane = threadIdx.x & 63;
  if (wid >= NN) return;
  float v = fmaxf(buf[(size_t)wid * 64 + lane] + b2[lane], 0.f);
  float m = v;
#pragma unroll
  for (int off = 32; off > 0; off >>= 1) m = fmaxf(m, __shfl_xor(m, off));
  float e = expf(v - m);
  float ss = e;
#pragma unroll
  for (int off = 32; off > 0; off >>= 1) ss += __shfl_xor(ss, off);
  buf[(size_t)wid * 64 + lane] = (v - m) - logf(ss);
}

// ---------------- launch ----------------

extern "C" void kernel_launch(void* const* d_in, const int* in_sizes, int n_in,
                              void* d_out, int out_size, void* d_ws, size_t ws_size,
                              hipStream_t stream) {
  const float* x  = (const float*)d_in[0];
  const int*   ei = (const int*)d_in[1];
  const float* W0 = (const float*)d_in[2];
  const float* b0 = (const float*)d_in[3];
  const float* W1 = (const float*)d_in[4];
  const float* b1 = (const float*)d_in[5];
  const float* W2 = (const float*)d_in[6];
  const float* b2 = (const float*)d_in[7];
  const int* esrc = ei;        // edge_index[0]
  const int* edst = ei + NE;   // edge_index[1]

  // Workspace (~33.6 MB). Aliases: bucketed (12.8 MB) in tmp (dead until first GEMM);
  // bhist+blockbase (1.6 MB) in csr_src (dead until k_csrfill, which runs after their last use).
  char* p = (char*)d_ws;
  auto alloc = [&](size_t bytes) {
    char* q = p;
    p += (bytes + 255) & ~(size_t)255;
    return q;
  };
  int*    counts  = (int*)alloc((size_t)NN * 4);            // 0.4 MB
  float*  dis     = (float*)alloc((size_t)NN * 4);          // 0.4 MB
  int*    row_ptr = (int*)alloc((size_t)(NN + 1) * 4);      // 0.4 MB
  int*    bsums   = (int*)alloc(512 * 4);
  int*    btot    = (int*)alloc(NBK * 4);
  int*    bptr    = (int*)alloc((NBK + 1) * 4);
  int*    csr_src = (int*)alloc((size_t)NE * 4);            // 6.4 MB
  __bf16* tmp     = (__bf16*)alloc((size_t)NN * 128 * 2);   // 25.6 MB
  int2*   bucketed  = (int2*)tmp;                           // 12.8 MB alias
  int*    bhist     = csr_src;                              // 800 KB alias
  int*    blockbase = csr_src + NBLK * NBK;                 // 800 KB alias

  k1_hist<<<NBLK, 256, 0, stream>>>(edst, bhist);
  kA_btot<<<NBK, 256, 0, stream>>>(bhist, btot);
  kB_bscan<<<1, 1024, 0, stream>>>(btot, bptr);
  kC_bbase<<<NBK, 256, 0, stream>>>(bhist, bptr, blockbase);
  k3_scatter<<<NBLK, 256, 0, stream>>>(esrc, edst, blockbase, bucketed);
  k_deg<<<NBK, 256, 0, stream>>>(bucketed, bptr, counts, dis);
  k_scan_block<<<SCAN_BLOCKS, 256, 0, stream>>>(counts, row_ptr, bsums);
  k_scan_bsums<<<1, 512, 0, stream>>>(bsums);
  k_scan_add<<<SCAN_BLOCKS, 256, 0, stream>>>(row_ptr, bsums);
  k_csrfill<<<NBK, 256, 0, stream>>>(bucketed, bptr, row_ptr, csr_src);

  int gblocks = (NN + 127) / 128;
  int ablocks = (NN * 64 + 255) / 256;

  k_gemm<128, 0><<<gblocks, 256, 0, stream>>>(x, W0, nullptr, dis, tmp);
  k_agg<128><<<ablocks, 256, 0, stream>>>(tmp, row_ptr, csr_src, dis, d_out);  // agg1 bf16 in d_out

  k_gemm<128, 2><<<gblocks, 256, 0, stream>>>(d_out, W1, b0, dis, tmp);
  k_agg<128><<<ablocks, 256, 0, stream>>>(tmp, row_ptr, csr_src, dis, d_out);  // agg2 bf16 in d_out

  k_gemm<64, 2><<<gblocks, 256, 0, stream>>>(d_out, W2, b1, dis, tmp);
  k_agg<64><<<ablocks, 256, 0, stream>>>(tmp, row_ptr, csr_src, dis, d_out);   // agg3 fp32 in d_out

  k_final<<<ablocks, 256, 0, stream>>>((float*)d_out, b2);                     // in-place
}

// Round 8
// 454.971 us; speedup vs baseline: 2.8587x; 1.2766x over previous
//
#include <hip/hip_runtime.h>

#define NN 100000
#define NE 1600000
#define NBK 782   // ceil(NN/128) 128-node buckets
#define NBLK 256  // persistent blocks for counting sort
#define CHUNK ((NE + NBLK - 1) / NBLK)  // 6250 (exact: 256*6250 = 1.6M)

typedef __bf16 bf16x2 __attribute__((ext_vector_type(2)));
typedef __bf16 bf16x4 __attribute__((ext_vector_type(4)));
typedef __bf16 bf16x8 __attribute__((ext_vector_type(8)));
typedef float f32x4 __attribute__((ext_vector_type(4)));

constexpr int SCAN_BLOCKS = (NN + 255) / 256;  // 391

// ---------------- privatized counting sort by dst-bucket ----------------
// Zero contended global atomics (r6 lesson: 1.6M global atomics on packed
// counters serialize). Edge record packed: (src << 7) | (dst & 127).

__global__ __launch_bounds__(256) void k1_hist(const int* __restrict__ dst, int* __restrict__ bhist) {
  __shared__ int h[NBK];
  int tid = threadIdx.x, b = blockIdx.x;
  for (int i = tid; i < NBK; i += 256) h[i] = 0;
  __syncthreads();
  int base = b * CHUNK, end = min(base + CHUNK, NE);
  for (int e = base + tid; e < end; e += 256) atomicAdd(&h[dst[e] >> 7], 1);
  __syncthreads();
  for (int i = tid; i < NBK; i += 256) bhist[b * NBK + i] = h[i];  // [block][bin] contiguous
}

__global__ __launch_bounds__(256) void kA_btot(const int* __restrict__ bhist, int* __restrict__ btot) {
  __shared__ int s[256];
  int bin = blockIdx.x, tid = threadIdx.x;
  s[tid] = bhist[tid * NBK + bin];  // NBLK == 256 == blockDim
  __syncthreads();
  for (int off = 128; off > 0; off >>= 1) {
    if (tid < off) s[tid] += s[tid + off];
    __syncthreads();
  }
  if (tid == 0) btot[bin] = s[0];
}

__global__ __launch_bounds__(1024) void kB_bscan(const int* __restrict__ btot, int* __restrict__ bptr) {
  __shared__ int s[1024];
  int tid = threadIdx.x;
  int v = (tid < NBK) ? btot[tid] : 0;
  s[tid] = v;
  __syncthreads();
  for (int off = 1; off < 1024; off <<= 1) {
    int t = (tid >= off) ? s[tid - off] : 0;
    __syncthreads();
    s[tid] += t;
    __syncthreads();
  }
  if (tid < NBK) bptr[tid + 1] = s[tid];
  if (tid == 0) bptr[0] = 0;
}

__global__ __launch_bounds__(256) void kC_bbase(const int* __restrict__ bhist, const int* __restrict__ bptr,
                                                int* __restrict__ blockbase) {
  __shared__ int s[256];
  int bin = blockIdx.x, tid = threadIdx.x;
  int v = bhist[tid * NBK + bin];
  s[tid] = v;
  __syncthreads();
  for (int off = 1; off < 256; off <<= 1) {
    int t = (tid >= off) ? s[tid - off] : 0;
    __syncthreads();
    s[tid] += t;
    __syncthreads();
  }
  blockbase[bin * NBLK + tid] = bptr[bin] + s[tid] - v;  // exclusive
}

// scatter packed edges into bucket-contiguous segments via LDS cursors
__global__ __launch_bounds__(256) void k3_scatter(const int* __restrict__ src, const int* __restrict__ dst,
                                                  const int* __restrict__ blockbase, int* __restrict__ bucketed) {
  __shared__ int cur[NBK];
  int tid = threadIdx.x, b = blockIdx.x;
  for (int i = tid; i < NBK; i += 256) cur[i] = blockbase[i * NBLK + b];
  __syncthreads();
  int base = b * CHUNK, end = min(base + CHUNK, NE);
  for (int e = base + tid; e < end; e += 256) {
    int d = dst[e];
    int pos = atomicAdd(&cur[d >> 7], 1);
    bucketed[pos] = (src[e] << 7) | (d & 127);  // src < 2^17, local dst 7 bits
  }
}

// one block per bucket: LDS histogram -> per-node degree + dis
__global__ __launch_bounds__(256) void k_deg(const int* __restrict__ bucketed, const int* __restrict__ bptr,
                                             int* __restrict__ counts, float* __restrict__ dis) {
  __shared__ int deg[128];
  int b = blockIdx.x, tid = threadIdx.x;
  int nb0 = b << 7;
  if (tid < 128) deg[tid] = 0;
  __syncthreads();
  int beg = bptr[b], end = bptr[b + 1];
  for (int e = beg + tid; e < end; e += 256) atomicAdd(&deg[bucketed[e] & 127], 1);
  __syncthreads();
  if (tid < 128 && nb0 + tid < NN) {
    int dg = deg[tid];
    counts[nb0 + tid] = dg;
    dis[nb0 + tid] = rsqrtf((float)(dg + 1));  // +1 self-loop
  }
}

// one block per bucket: LDS cursors from row_ptr; csr region is L2-resident
__global__ __launch_bounds__(256) void k_csrfill(const int* __restrict__ bucketed, const int* __restrict__ bptr,
                                                 const int* __restrict__ row_ptr, int* __restrict__ csr_src) {
  __shared__ int cur[128];
  int b = blockIdx.x, tid = threadIdx.x;
  int nb0 = b << 7;
  if (tid < 128 && nb0 + tid < NN) cur[tid] = row_ptr[nb0 + tid];
  __syncthreads();
  int beg = bptr[b], end = bptr[b + 1];
  for (int e = beg + tid; e < end; e += 256) {
    int pk = bucketed[e];
    int pos = atomicAdd(&cur[pk & 127], 1);
    csr_src[pos] = pk >> 7;
  }
}

// ---------------- node-level scan (counts -> row_ptr) ----------------

__global__ __launch_bounds__(256) void k_scan_block(const int* __restrict__ counts, int* __restrict__ row_ptr,
                                                    int* __restrict__ bsums) {
  __shared__ int s[256];
  int tid = threadIdx.x;
  int i = blockIdx.x * 256 + tid;
  int v = (i < NN) ? counts[i] : 0;
  s[tid] = v;
  __syncthreads();
  for (int off = 1; off < 256; off <<= 1) {
    int t = (tid >= off) ? s[tid - off] : 0;
    __syncthreads();
    s[tid] += t;
    __syncthreads();
  }
  if (i < NN) row_ptr[i + 1] = s[tid];
  if (tid == 255) bsums[blockIdx.x] = s[255];
}

__global__ __launch_bounds__(512) void k_scan_bsums(int* __restrict__ bsums) {
  __shared__ int s[512];
  int tid = threadIdx.x;
  int v = (tid < SCAN_BLOCKS) ? bsums[tid] : 0;
  s[tid] = v;
  __syncthreads();
  for (int off = 1; off < 512; off <<= 1) {
    int t = (tid >= off) ? s[tid - off] : 0;
    __syncthreads();
    s[tid] += t;
    __syncthreads();
  }
  bsums[tid] = s[tid];
}

__global__ __launch_bounds__(256) void k_scan_add(int* __restrict__ row_ptr, const int* __restrict__ bsums) {
  int i = blockIdx.x * 256 + threadIdx.x;
  if (i < NN && blockIdx.x > 0) row_ptr[i + 1] += bsums[blockIdx.x - 1];
  if (i == 0) row_ptr[0] = 0;
}

// ---------------- bf16 MFMA GEMM: tmp[m,n] = dis[m] * (xform(A[m,:]) @ W)[n] ----------------
// MODE 0: A fp32 [*,128], no transform (layer 1: A = x).
// MODE 2: A bf16 [*,128] (agg from previous layer, lives in d_out); xform = relu(a + bias[k]).

template <int BN, int MODE>
__global__ __launch_bounds__(256) void k_gemm(const void* __restrict__ Av, const float* __restrict__ W,
                                              const float* __restrict__ bias, const float* __restrict__ dis,
                                              __bf16* __restrict__ out) {
  constexpr int LDK = 72;  // 64 + 8 pad
  constexpr int NSH = (BN == 128) ? 7 : 6;
  constexpr int NT = BN / 32;
  __shared__ __bf16 lA[128 * LDK];
  __shared__ __bf16 lB[BN * LDK];

  const int tid = threadIdx.x;
  const int rowBase = blockIdx.x * 128;
  const int lane = tid & 63;
  const int wid = tid >> 6;
  const int wm = (wid & 1) * 64;
  const int wn = (wid >> 1) * (BN / 2);
  const int lm = lane & 15;
  const int kg = lane >> 4;

  f32x4 acc[4][NT] = {};

  for (int kb = 0; kb < 128; kb += 64) {
    if constexpr (MODE == 0) {
      const float* A = (const float*)Av;
      for (int i = tid; i < 128 * 16; i += 256) {
        int r = i >> 4;
        int c4 = (i & 15) * 4;
        int gr = rowBase + r;
        float4 v = make_float4(0.f, 0.f, 0.f, 0.f);
        if (gr < NN) v = *(const float4*)(A + (size_t)gr * 128 + kb + c4);
        bf16x4 bv = {(__bf16)v.x, (__bf16)v.y, (__bf16)v.z, (__bf16)v.w};
        *(bf16x4*)&lA[r * LDK + c4] = bv;
      }
    } else {
      const __bf16* A = (const __bf16*)Av;
      for (int i = tid; i < 128 * 8; i += 256) {
        int r = i >> 3;
        int c8 = (i & 7) * 8;
        int gr = rowBase + r;
        int gk = kb + c8;
        bf16x8 v = {};
        if (gr < NN) v = *(const bf16x8*)(A + (size_t)gr * 128 + gk);
        bf16x8 o;
#pragma unroll
        for (int j = 0; j < 8; ++j) o[j] = (__bf16)fmaxf((float)v[j] + bias[gk + j], 0.f);
        *(bf16x8*)&lA[r * LDK + c8] = o;
      }
    }
    for (int i = tid; i < 64 * BN; i += 256) {
      int n = i & (BN - 1);
      int k = i >> NSH;
      lB[n * LDK + k] = (__bf16)W[(size_t)(kb + k) * BN + n];
    }
    __syncthreads();
#pragma unroll
    for (int kk = 0; kk < 64; kk += 32) {
      bf16x8 af[4], bfr[NT];
#pragma unroll
      for (int tm = 0; tm < 4; ++tm)
        af[tm] = *(const bf16x8*)&lA[(wm + tm * 16 + lm) * LDK + kk + kg * 8];
#pragma unroll
      for (int tn = 0; tn < NT; ++tn)
        bfr[tn] = *(const bf16x8*)&lB[(wn + tn * 16 + lm) * LDK + kk + kg * 8];
#pragma unroll
      for (int tm = 0; tm < 4; ++tm)
#pragma unroll
        for (int tn = 0; tn < NT; ++tn)
          acc[tm][tn] = __builtin_amdgcn_mfma_f32_16x16x32_bf16(af[tm], bfr[tn], acc[tm][tn], 0, 0, 0);
    }
    __syncthreads();
  }

#pragma unroll
  for (int tm = 0; tm < 4; ++tm) {
    int r0 = rowBase + wm + tm * 16 + kg * 4;
#pragma unroll
    for (int tn = 0; tn < NT; ++tn) {
      int c0 = wn + tn * 16 + lm;
#pragma unroll
      for (int r = 0; r < 4; ++r) {
        int gr = r0 + r;
        if (gr < NN) out[(size_t)gr * BN + c0] = (__bf16)(acc[tm][tn][r] * dis[gr]);
      }
    }
  }
}

// ---------------- pull aggregation, 8-deep gather pipeline ----------------
// r7 counters: VALUBusy 27%, hbm 26% -> latency-bound. Unroll-by-8 puts 8
// independent row-gathers in flight per wave.

template <int F>
__global__ __launch_bounds__(256) void k_agg(const __bf16* __restrict__ tmp, const int* __restrict__ row_ptr,
                                             const int* __restrict__ csr_src, const float* __restrict__ dis,
                                             void* __restrict__ aggv) {
  int wid = (blockIdx.x * 256 + threadIdx.x) >> 6;
  int lane = threadIdx.x & 63;
  if (wid >= NN) return;
  int beg = row_ptr[wid];
  int end = row_ptr[wid + 1];
  if constexpr (F == 128) {
    bf16x2 sv = *(const bf16x2*)&tmp[(size_t)wid * 128 + lane * 2];
    float ax = (float)sv[0], ay = (float)sv[1];
    for (int base = beg; base < end; base += 64) {
      int cnt = min(64, end - base);
      int sidx = (base + lane < end) ? csr_src[base + lane] : 0;
      int j = 0;
      for (; j + 8 <= cnt; j += 8) {
        int s0 = __shfl(sidx, j + 0), s1 = __shfl(sidx, j + 1);
        int s2 = __shfl(sidx, j + 2), s3 = __shfl(sidx, j + 3);
        int s4 = __shfl(sidx, j + 4), s5 = __shfl(sidx, j + 5);
        int s6 = __shfl(sidx, j + 6), s7 = __shfl(sidx, j + 7);
        bf16x2 v0 = *(const bf16x2*)&tmp[(size_t)s0 * 128 + lane * 2];
        bf16x2 v1 = *(const bf16x2*)&tmp[(size_t)s1 * 128 + lane * 2];
        bf16x2 v2 = *(const bf16x2*)&tmp[(size_t)s2 * 128 + lane * 2];
        bf16x2 v3 = *(const bf16x2*)&tmp[(size_t)s3 * 128 + lane * 2];
        bf16x2 v4 = *(const bf16x2*)&tmp[(size_t)s4 * 128 + lane * 2];
        bf16x2 v5 = *(const bf16x2*)&tmp[(size_t)s5 * 128 + lane * 2];
        bf16x2 v6 = *(const bf16x2*)&tmp[(size_t)s6 * 128 + lane * 2];
        bf16x2 v7 = *(const bf16x2*)&tmp[(size_t)s7 * 128 + lane * 2];
        ax += (float)v0[0] + (float)v1[0] + (float)v2[0] + (float)v3[0] +
              (float)v4[0] + (float)v5[0] + (float)v6[0] + (float)v7[0];
        ay += (float)v0[1] + (float)v1[1] + (float)v2[1] + (float)v3[1] +
              (float)v4[1] + (float)v5[1] + (float)v6[1] + (float)v7[1];
      }
      for (; j < cnt; ++j) {
        int s = __shfl(sidx, j);
        bf16x2 v = *(const bf16x2*)&tmp[(size_t)s * 128 + lane * 2];
        ax += (float)v[0];
        ay += (float)v[1];
      }
    }
    float d = dis[wid];
    bf16x2 o = {(__bf16)(ax * d), (__bf16)(ay * d)};
    *(bf16x2*)((__bf16*)aggv + (size_t)wid * 128 + lane * 2) = o;
  } else {
    float a = (float)tmp[(size_t)wid * 64 + lane];
    for (int base = beg; base < end; base += 64) {
      int cnt = min(64, end - base);
      int sidx = (base + lane < end) ? csr_src[base + lane] : 0;
      int j = 0;
      for (; j + 8 <= cnt; j += 8) {
        int s0 = __shfl(sidx, j + 0), s1 = __shfl(sidx, j + 1);
        int s2 = __shfl(sidx, j + 2), s3 = __shfl(sidx, j + 3);
        int s4 = __shfl(sidx, j + 4), s5 = __shfl(sidx, j + 5);
        int s6 = __shfl(sidx, j + 6), s7 = __shfl(sidx, j + 7);
        float v0 = (float)tmp[(size_t)s0 * 64 + lane];
        float v1 = (float)tmp[(size_t)s1 * 64 + lane];
        float v2 = (float)tmp[(size_t)s2 * 64 + lane];
        float v3 = (float)tmp[(size_t)s3 * 64 + lane];
        float v4 = (float)tmp[(size_t)s4 * 64 + lane];
        float v5 = (float)tmp[(size_t)s5 * 64 + lane];
        float v6 = (float)tmp[(size_t)s6 * 64 + lane];
        float v7 = (float)tmp[(size_t)s7 * 64 + lane];
        a += v0 + v1 + v2 + v3 + v4 + v5 + v6 + v7;
      }
      for (; j < cnt; ++j) {
        int s = __shfl(sidx, j);
        a += (float)tmp[(size_t)s * 64 + lane];
      }
    }
    ((float*)aggv)[(size_t)wid * 64 + lane] = a * dis[wid];
  }
}

// ---------------- final (in-place on d_out): relu(agg + b2) -> log_softmax ----------------

__global__ __launch_bounds__(256) void k_final(float* __restrict__ buf, const float* __restrict__ b2) {
  int wid = (blockIdx.x * 256 + threadIdx.x) >> 6;
  int lane = threadIdx.x & 63;
  if (wid >= NN) return;
  float v = fmaxf(buf[(size_t)wid * 64 + lane] + b2[lane], 0.f);
  float m = v;
#pragma unroll
  for (int off = 32; off > 0; off >>= 1) m = fmaxf(m, __shfl_xor(m, off));
  float e = expf(v - m);
  float ss = e;
#pragma unroll
  for (int off = 32; off > 0; off >>= 1) ss += __shfl_xor(ss, off);
  buf[(size_t)wid * 64 + lane] = (v - m) - logf(ss);
}

// ---------------- launch ----------------

extern "C" void kernel_launch(void* const* d_in, const int* in_sizes, int n_in,
                              void* d_out, int out_size, void* d_ws, size_t ws_size,
                              hipStream_t stream) {
  const float* x  = (const float*)d_in[0];
  const int*   ei = (const int*)d_in[1];
  const float* W0 = (const float*)d_in[2];
  const float* b0 = (const float*)d_in[3];
  const float* W1 = (const float*)d_in[4];
  const float* b1 = (const float*)d_in[5];
  const float* W2 = (const float*)d_in[6];
  const float* b2 = (const float*)d_in[7];
  const int* esrc = ei;
  const int* edst = ei + NE;

  char* p = (char*)d_ws;
  auto alloc = [&](size_t bytes) {
    char* q = p;
    p += (bytes + 255) & ~(size_t)255;
    return q;
  };
  int*    counts  = (int*)alloc((size_t)NN * 4);
  float*  dis     = (float*)alloc((size_t)NN * 4);
  int*    row_ptr = (int*)alloc((size_t)(NN + 1) * 4);
  int*    bsums   = (int*)alloc(512 * 4);
  int*    btot    = (int*)alloc(NBK * 4);
  int*    bptr    = (int*)alloc((NBK + 1) * 4);
  int*    csr_src = (int*)alloc((size_t)NE * 4);            // 6.4 MB
  __bf16* tmp     = (__bf16*)alloc((size_t)NN * 128 * 2);   // 25.6 MB
  int*    bucketed  = (int*)tmp;                            // 6.4 MB alias (packed edges)
  int*    bhist     = csr_src;                              // 800 KB alias
  int*    blockbase = csr_src + NBLK * NBK;                 // 800 KB alias

  k1_hist<<<NBLK, 256, 0, stream>>>(edst, bhist);
  kA_btot<<<NBK, 256, 0, stream>>>(bhist, btot);
  kB_bscan<<<1, 1024, 0, stream>>>(btot, bptr);
  kC_bbase<<<NBK, 256, 0, stream>>>(bhist, bptr, blockbase);
  k3_scatter<<<NBLK, 256, 0, stream>>>(esrc, edst, blockbase, bucketed);
  k_deg<<<NBK, 256, 0, stream>>>(bucketed, bptr, counts, dis);
  k_scan_block<<<SCAN_BLOCKS, 256, 0, stream>>>(counts, row_ptr, bsums);
  k_scan_bsums<<<1, 512, 0, stream>>>(bsums);
  k_scan_add<<<SCAN_BLOCKS, 256, 0, stream>>>(row_ptr, bsums);
  k_csrfill<<<NBK, 256, 0, stream>>>(bucketed, bptr, row_ptr, csr_src);

  int gblocks = (NN + 127) / 128;
  int ablocks = (NN * 64 + 255) / 256;

  k_gemm<128, 0><<<gblocks, 256, 0, stream>>>(x, W0, nullptr, dis, tmp);
  k_agg<128><<<ablocks, 256, 0, stream>>>(tmp, row_ptr, csr_src, dis, d_out);

  k_gemm<128, 2><<<gblocks, 256, 0, stream>>>(d_out, W1, b0, dis, tmp);
  k_agg<128><<<ablocks, 256, 0, stream>>>(tmp, row_ptr, csr_src, dis, d_out);

  k_gemm<64, 2><<<gblocks, 256, 0, stream>>>(d_out, W2, b1, dis, tmp);
  k_agg<64><<<ablocks, 256, 0, stream>>>(tmp, row_ptr, csr_src, dis, d_out);

  k_final<<<ablocks, 256, 0, stream>>>((float*)d_out, b2);
}

// Round 9
// 437.780 us; speedup vs baseline: 2.9710x; 1.0393x over previous
//
#include <hip/hip_runtime.h>

#define NN 100000
#define NE 1600000
#define NBK 782   // ceil(NN/128) 128-node buckets
#define NBLK 256  // persistent blocks for counting sort
#define CHUNK ((NE + NBLK - 1) / NBLK)  // 6250

typedef __bf16 bf16x2 __attribute__((ext_vector_type(2)));
typedef __bf16 bf16x4 __attribute__((ext_vector_type(4)));
typedef __bf16 bf16x8 __attribute__((ext_vector_type(8)));
typedef float f32x4 __attribute__((ext_vector_type(4)));

constexpr int SCAN_BLOCKS = (NN + 255) / 256;  // 391

// ---------------- privatized counting sort by dst-bucket ----------------
// Zero contended global atomics. Edge record packed: (src << 7) | (dst & 127).

__global__ __launch_bounds__(256) void k1_hist(const int* __restrict__ dst, int* __restrict__ bhist) {
  __shared__ int h[NBK];
  int tid = threadIdx.x, b = blockIdx.x;
  for (int i = tid; i < NBK; i += 256) h[i] = 0;
  __syncthreads();
  int base = b * CHUNK, end = min(base + CHUNK, NE);
  for (int e = base + tid; e < end; e += 256) atomicAdd(&h[dst[e] >> 7], 1);
  __syncthreads();
  for (int i = tid; i < NBK; i += 256) bhist[b * NBK + i] = h[i];
}

__global__ __launch_bounds__(256) void kA_btot(const int* __restrict__ bhist, int* __restrict__ btot) {
  __shared__ int s[256];
  int bin = blockIdx.x, tid = threadIdx.x;
  s[tid] = bhist[tid * NBK + bin];
  __syncthreads();
  for (int off = 128; off > 0; off >>= 1) {
    if (tid < off) s[tid] += s[tid + off];
    __syncthreads();
  }
  if (tid == 0) btot[bin] = s[0];
}

__global__ __launch_bounds__(1024) void kB_bscan(const int* __restrict__ btot, int* __restrict__ bptr) {
  __shared__ int s[1024];
  int tid = threadIdx.x;
  int v = (tid < NBK) ? btot[tid] : 0;
  s[tid] = v;
  __syncthreads();
  for (int off = 1; off < 1024; off <<= 1) {
    int t = (tid >= off) ? s[tid - off] : 0;
    __syncthreads();
    s[tid] += t;
    __syncthreads();
  }
  if (tid < NBK) bptr[tid + 1] = s[tid];
  if (tid == 0) bptr[0] = 0;
}

__global__ __launch_bounds__(256) void kC_bbase(const int* __restrict__ bhist, const int* __restrict__ bptr,
                                                int* __restrict__ blockbase) {
  __shared__ int s[256];
  int bin = blockIdx.x, tid = threadIdx.x;
  int v = bhist[tid * NBK + bin];
  s[tid] = v;
  __syncthreads();
  for (int off = 1; off < 256; off <<= 1) {
    int t = (tid >= off) ? s[tid - off] : 0;
    __syncthreads();
    s[tid] += t;
    __syncthreads();
  }
  blockbase[bin * NBLK + tid] = bptr[bin] + s[tid] - v;
}

__global__ __launch_bounds__(256) void k3_scatter(const int* __restrict__ src, const int* __restrict__ dst,
                                                  const int* __restrict__ blockbase, int* __restrict__ bucketed) {
  __shared__ int cur[NBK];
  int tid = threadIdx.x, b = blockIdx.x;
  for (int i = tid; i < NBK; i += 256) cur[i] = blockbase[i * NBLK + b];
  __syncthreads();
  int base = b * CHUNK, end = min(base + CHUNK, NE);
  for (int e = base + tid; e < end; e += 256) {
    int d = dst[e];
    int pos = atomicAdd(&cur[d >> 7], 1);
    bucketed[pos] = (src[e] << 7) | (d & 127);
  }
}

__global__ __launch_bounds__(256) void k_deg(const int* __restrict__ bucketed, const int* __restrict__ bptr,
                                             int* __restrict__ counts, float* __restrict__ dis) {
  __shared__ int deg[128];
  int b = blockIdx.x, tid = threadIdx.x;
  int nb0 = b << 7;
  if (tid < 128) deg[tid] = 0;
  __syncthreads();
  int beg = bptr[b], end = bptr[b + 1];
  for (int e = beg + tid; e < end; e += 256) atomicAdd(&deg[bucketed[e] & 127], 1);
  __syncthreads();
  if (tid < 128 && nb0 + tid < NN) {
    int dg = deg[tid];
    counts[nb0 + tid] = dg;
    dis[nb0 + tid] = rsqrtf((float)(dg + 1));
  }
}

__global__ __launch_bounds__(256) void k_csrfill(const int* __restrict__ bucketed, const int* __restrict__ bptr,
                                                 const int* __restrict__ row_ptr, int* __restrict__ csr_src) {
  __shared__ int cur[128];
  int b = blockIdx.x, tid = threadIdx.x;
  int nb0 = b << 7;
  if (tid < 128 && nb0 + tid < NN) cur[tid] = row_ptr[nb0 + tid];
  __syncthreads();
  int beg = bptr[b], end = bptr[b + 1];
  for (int e = beg + tid; e < end; e += 256) {
    int pk = bucketed[e];
    int pos = atomicAdd(&cur[pk & 127], 1);
    csr_src[pos] = pk >> 7;
  }
}

// ---------------- node-level scan (counts -> row_ptr) ----------------

__global__ __launch_bounds__(256) void k_scan_block(const int* __restrict__ counts, int* __restrict__ row_ptr,
                                                    int* __restrict__ bsums) {
  __shared__ int s[256];
  int tid = threadIdx.x;
  int i = blockIdx.x * 256 + tid;
  int v = (i < NN) ? counts[i] : 0;
  s[tid] = v;
  __syncthreads();
  for (int off = 1; off < 256; off <<= 1) {
    int t = (tid >= off) ? s[tid - off] : 0;
    __syncthreads();
    s[tid] += t;
    __syncthreads();
  }
  if (i < NN) row_ptr[i + 1] = s[tid];
  if (tid == 255) bsums[blockIdx.x] = s[255];
}

__global__ __launch_bounds__(512) void k_scan_bsums(int* __restrict__ bsums) {
  __shared__ int s[512];
  int tid = threadIdx.x;
  int v = (tid < SCAN_BLOCKS) ? bsums[tid] : 0;
  s[tid] = v;
  __syncthreads();
  for (int off = 1; off < 512; off <<= 1) {
    int t = (tid >= off) ? s[tid - off] : 0;
    __syncthreads();
    s[tid] += t;
    __syncthreads();
  }
  bsums[tid] = s[tid];
}

__global__ __launch_bounds__(256) void k_scan_add(int* __restrict__ row_ptr, const int* __restrict__ bsums) {
  int i = blockIdx.x * 256 + threadIdx.x;
  if (i < NN && blockIdx.x > 0) row_ptr[i + 1] += bsums[blockIdx.x - 1];
  if (i == 0) row_ptr[0] = 0;
}

// ---------------- bf16 MFMA GEMM: tmp[m,n] = dis[m] * (xform(A[m,:]) @ W)[n] ----------------

template <int BN, int MODE>
__global__ __launch_bounds__(256) void k_gemm(const void* __restrict__ Av, const float* __restrict__ W,
                                              const float* __restrict__ bias, const float* __restrict__ dis,
                                              __bf16* __restrict__ out) {
  constexpr int LDK = 72;
  constexpr int NSH = (BN == 128) ? 7 : 6;
  constexpr int NT = BN / 32;
  __shared__ __bf16 lA[128 * LDK];
  __shared__ __bf16 lB[BN * LDK];

  const int tid = threadIdx.x;
  const int rowBase = blockIdx.x * 128;
  const int lane = tid & 63;
  const int wid = tid >> 6;
  const int wm = (wid & 1) * 64;
  const int wn = (wid >> 1) * (BN / 2);
  const int lm = lane & 15;
  const int kg = lane >> 4;

  f32x4 acc[4][NT] = {};

  for (int kb = 0; kb < 128; kb += 64) {
    if constexpr (MODE == 0) {
      const float* A = (const float*)Av;
      for (int i = tid; i < 128 * 16; i += 256) {
        int r = i >> 4;
        int c4 = (i & 15) * 4;
        int gr = rowBase + r;
        float4 v = make_float4(0.f, 0.f, 0.f, 0.f);
        if (gr < NN) v = *(const float4*)(A + (size_t)gr * 128 + kb + c4);
        bf16x4 bv = {(__bf16)v.x, (__bf16)v.y, (__bf16)v.z, (__bf16)v.w};
        *(bf16x4*)&lA[r * LDK + c4] = bv;
      }
    } else {
      const __bf16* A = (const __bf16*)Av;
      for (int i = tid; i < 128 * 8; i += 256) {
        int r = i >> 3;
        int c8 = (i & 7) * 8;
        int gr = rowBase + r;
        int gk = kb + c8;
        bf16x8 v = {};
        if (gr < NN) v = *(const bf16x8*)(A + (size_t)gr * 128 + gk);
        bf16x8 o;
#pragma unroll
        for (int j = 0; j < 8; ++j) o[j] = (__bf16)fmaxf((float)v[j] + bias[gk + j], 0.f);
        *(bf16x8*)&lA[r * LDK + c8] = o;
      }
    }
    for (int i = tid; i < 64 * BN; i += 256) {
      int n = i & (BN - 1);
      int k = i >> NSH;
      lB[n * LDK + k] = (__bf16)W[(size_t)(kb + k) * BN + n];
    }
    __syncthreads();
#pragma unroll
    for (int kk = 0; kk < 64; kk += 32) {
      bf16x8 af[4], bfr[NT];
#pragma unroll
      for (int tm = 0; tm < 4; ++tm)
        af[tm] = *(const bf16x8*)&lA[(wm + tm * 16 + lm) * LDK + kk + kg * 8];
#pragma unroll
      for (int tn = 0; tn < NT; ++tn)
        bfr[tn] = *(const bf16x8*)&lB[(wn + tn * 16 + lm) * LDK + kk + kg * 8];
#pragma unroll
      for (int tm = 0; tm < 4; ++tm)
#pragma unroll
        for (int tn = 0; tn < NT; ++tn)
          acc[tm][tn] = __builtin_amdgcn_mfma_f32_16x16x32_bf16(af[tm], bfr[tn], acc[tm][tn], 0, 0, 0);
    }
    __syncthreads();
  }

#pragma unroll
  for (int tm = 0; tm < 4; ++tm) {
    int r0 = rowBase + wm + tm * 16 + kg * 4;
#pragma unroll
    for (int tn = 0; tn < NT; ++tn) {
      int c0 = wn + tn * 16 + lm;
#pragma unroll
      for (int r = 0; r < 4; ++r) {
        int gr = r0 + r;
        if (gr < NN) out[(size_t)gr * BN + c0] = (__bf16)(acc[tm][tn][r] * dis[gr]);
      }
    }
  }
}

// ---------------- grouped pull aggregation (F=128) ----------------
// 4 groups x 16 lanes; each group gathers a different edge's 256 B row with
// 16 B/lane loads -> 4 rows (1 KB) per wave-instruction, 4-deep unroll = 16
// edges / 4 KB in flight. Cross-group combine via 2 shfl_xor rounds at end.

__global__ __launch_bounds__(256) void k_agg128(const __bf16* __restrict__ tmp, const int* __restrict__ row_ptr,
                                                const int* __restrict__ csr_src, const float* __restrict__ dis,
                                                __bf16* __restrict__ agg) {
  int wid = (blockIdx.x * 256 + threadIdx.x) >> 6;
  int lane = threadIdx.x & 63;
  if (wid >= NN) return;
  int grp = lane >> 4;   // 0..3
  int fl = lane & 15;    // features [fl*8, fl*8+8)

  float acc[8];
  if (grp == 0) {
    bf16x8 sv = *(const bf16x8*)&tmp[(size_t)wid * 128 + fl * 8];
#pragma unroll
    for (int t = 0; t < 8; ++t) acc[t] = (float)sv[t];
  } else {
#pragma unroll
    for (int t = 0; t < 8; ++t) acc[t] = 0.f;
  }

  int beg = row_ptr[wid];
  int end = row_ptr[wid + 1];
  for (int base = beg; base < end; base += 64) {
    int cnt = min(64, end - base);
    int sidx = (base + lane < end) ? csr_src[base + lane] : 0;
    int i = 0;
    // 16-edge unrolled chunks: 4 independent 1 KB gathers in flight
    for (; i + 16 <= cnt; i += 16) {
      bf16x8 v[4];
#pragma unroll
      for (int u = 0; u < 4; ++u) {
        int s = __shfl(sidx, i + u * 4 + grp);
        v[u] = *(const bf16x8*)&tmp[(size_t)s * 128 + fl * 8];
      }
#pragma unroll
      for (int u = 0; u < 4; ++u)
#pragma unroll
        for (int t = 0; t < 8; ++t) acc[t] += (float)v[u][t];
    }
    // 4-edge chunks
    for (; i + 4 <= cnt; i += 4) {
      int s = __shfl(sidx, i + grp);
      bf16x8 v = *(const bf16x8*)&tmp[(size_t)s * 128 + fl * 8];
#pragma unroll
      for (int t = 0; t < 8; ++t) acc[t] += (float)v[t];
    }
    // tail 1-3 edges, predicated per group
    if (i < cnt) {
      int idx = i + grp;
      int s = __shfl(sidx, idx & 63);
      if (idx < cnt) {
        bf16x8 v = *(const bf16x8*)&tmp[(size_t)s * 128 + fl * 8];
#pragma unroll
        for (int t = 0; t < 8; ++t) acc[t] += (float)v[t];
      }
    }
  }

  // combine the 4 group partials (xor over lane bits 4,5)
#pragma unroll
  for (int t = 0; t < 8; ++t) acc[t] += __shfl_xor(acc[t], 16);
#pragma unroll
  for (int t = 0; t < 8; ++t) acc[t] += __shfl_xor(acc[t], 32);

  if (grp == 0) {
    float d = dis[wid];
    bf16x8 o;
#pragma unroll
    for (int t = 0; t < 8; ++t) o[t] = (__bf16)(acc[t] * d);
    *(bf16x8*)&agg[(size_t)wid * 128 + fl * 8] = o;
  }
}

// ---------------- F=64 aggregation fused with bias+relu+log_softmax ----------------
// One wave per node, lane = feature. 8-deep gather unroll; epilogue fused
// (saves the separate k_final pass: 51 MB of traffic + a launch).

__global__ __launch_bounds__(256) void k_agg64_final(const __bf16* __restrict__ tmp, const int* __restrict__ row_ptr,
                                                     const int* __restrict__ csr_src, const float* __restrict__ dis,
                                                     const float* __restrict__ b2, float* __restrict__ out) {
  int wid = (blockIdx.x * 256 + threadIdx.x) >> 6;
  int lane = threadIdx.x & 63;
  if (wid >= NN) return;
  int beg = row_ptr[wid];
  int end = row_ptr[wid + 1];
  float a = (float)tmp[(size_t)wid * 64 + lane];
  for (int base = beg; base < end; base += 64) {
    int cnt = min(64, end - base);
    int sidx = (base + lane < end) ? csr_src[base + lane] : 0;
    int j = 0;
    for (; j + 8 <= cnt; j += 8) {
      int s0 = __shfl(sidx, j + 0), s1 = __shfl(sidx, j + 1);
      int s2 = __shfl(sidx, j + 2), s3 = __shfl(sidx, j + 3);
      int s4 = __shfl(sidx, j + 4), s5 = __shfl(sidx, j + 5);
      int s6 = __shfl(sidx, j + 6), s7 = __shfl(sidx, j + 7);
      float v0 = (float)tmp[(size_t)s0 * 64 + lane];
      float v1 = (float)tmp[(size_t)s1 * 64 + lane];
      float v2 = (float)tmp[(size_t)s2 * 64 + lane];
      float v3 = (float)tmp[(size_t)s3 * 64 + lane];
      float v4 = (float)tmp[(size_t)s4 * 64 + lane];
      float v5 = (float)tmp[(size_t)s5 * 64 + lane];
      float v6 = (float)tmp[(size_t)s6 * 64 + lane];
      float v7 = (float)tmp[(size_t)s7 * 64 + lane];
      a += v0 + v1 + v2 + v3 + v4 + v5 + v6 + v7;
    }
    for (; j < cnt; ++j) {
      int s = __shfl(sidx, j);
      a += (float)tmp[(size_t)s * 64 + lane];
    }
  }
  // fused epilogue: relu(agg*dis + b2) -> log_softmax
  float v = fmaxf(a * dis[wid] + b2[lane], 0.f);
  float m = v;
#pragma unroll
  for (int off = 32; off > 0; off >>= 1) m = fmaxf(m, __shfl_xor(m, off));
  float e = expf(v - m);
  float ss = e;
#pragma unroll
  for (int off = 32; off > 0; off >>= 1) ss += __shfl_xor(ss, off);
  out[(size_t)wid * 64 + lane] = (v - m) - logf(ss);
}

// ---------------- launch ----------------

extern "C" void kernel_launch(void* const* d_in, const int* in_sizes, int n_in,
                              void* d_out, int out_size, void* d_ws, size_t ws_size,
                              hipStream_t stream) {
  const float* x  = (const float*)d_in[0];
  const int*   ei = (const int*)d_in[1];
  const float* W0 = (const float*)d_in[2];
  const float* b0 = (const float*)d_in[3];
  const float* W1 = (const float*)d_in[4];
  const float* b1 = (const float*)d_in[5];
  const float* W2 = (const float*)d_in[6];
  const float* b2 = (const float*)d_in[7];
  const int* esrc = ei;
  const int* edst = ei + NE;

  char* p = (char*)d_ws;
  auto alloc = [&](size_t bytes) {
    char* q = p;
    p += (bytes + 255) & ~(size_t)255;
    return q;
  };
  int*    counts  = (int*)alloc((size_t)NN * 4);
  float*  dis     = (float*)alloc((size_t)NN * 4);
  int*    row_ptr = (int*)alloc((size_t)(NN + 1) * 4);
  int*    bsums   = (int*)alloc(512 * 4);
  int*    btot    = (int*)alloc(NBK * 4);
  int*    bptr    = (int*)alloc((NBK + 1) * 4);
  int*    csr_src = (int*)alloc((size_t)NE * 4);            // 6.4 MB
  __bf16* tmp     = (__bf16*)alloc((size_t)NN * 128 * 2);   // 25.6 MB
  int*    bucketed  = (int*)tmp;                            // 6.4 MB alias (packed edges)
  int*    bhist     = csr_src;                              // 800 KB alias
  int*    blockbase = csr_src + NBLK * NBK;                 // 800 KB alias

  k1_hist<<<NBLK, 256, 0, stream>>>(edst, bhist);
  kA_btot<<<NBK, 256, 0, stream>>>(bhist, btot);
  kB_bscan<<<1, 1024, 0, stream>>>(btot, bptr);
  kC_bbase<<<NBK, 256, 0, stream>>>(bhist, bptr, blockbase);
  k3_scatter<<<NBLK, 256, 0, stream>>>(esrc, edst, blockbase, bucketed);
  k_deg<<<NBK, 256, 0, stream>>>(bucketed, bptr, counts, dis);
  k_scan_block<<<SCAN_BLOCKS, 256, 0, stream>>>(counts, row_ptr, bsums);
  k_scan_bsums<<<1, 512, 0, stream>>>(bsums);
  k_scan_add<<<SCAN_BLOCKS, 256, 0, stream>>>(row_ptr, bsums);
  k_csrfill<<<NBK, 256, 0, stream>>>(bucketed, bptr, row_ptr, csr_src);

  int gblocks = (NN + 127) / 128;
  int ablocks = (NN * 64 + 255) / 256;

  k_gemm<128, 0><<<gblocks, 256, 0, stream>>>(x, W0, nullptr, dis, tmp);
  k_agg128<<<ablocks, 256, 0, stream>>>(tmp, row_ptr, csr_src, dis, (__bf16*)d_out);

  k_gemm<128, 2><<<gblocks, 256, 0, stream>>>(d_out, W1, b0, dis, tmp);
  k_agg128<<<ablocks, 256, 0, stream>>>(tmp, row_ptr, csr_src, dis, (__bf16*)d_out);

  k_gemm<64, 2><<<gblocks, 256, 0, stream>>>(d_out, W2, b1, dis, tmp);
  k_agg64_final<<<ablocks, 256, 0, stream>>>(tmp, row_ptr, csr_src, dis, b2, (float*)d_out);
}